// Round 3
// baseline (5397.957 us; speedup 1.0000x reference)
//
#include <hip/hip_runtime.h>
#include <hip/hip_bf16.h>
#include <math.h>

// ---------------------------------------------------------------------------
// GCN 2-layer forward, bf16 MFMA GEMM1 + bf16 activations.
// R7: spmm1 rewritten as src-blocked LDS-accumulator aggregation.
//   Evidence: spmm1 gather requested 1.64GB, FETCH stuck at 755MB (LLC
//   thrash: consumers of a support row are spread over the whole kernel).
//   Fix: edges grouped by (64-dst bucket, src>>12 block); all bucket-blocks
//   sweep src-blocks in phase -> support rows consumed while L2-resident.
//   Per-block acc[64][256] f32 = 64KB LDS; wave owns a 64-feat slice (no
//   cross-wave races); LDS atomicAdd f32 with bank-parity ordering
//   (conflict-free). CSR: buckets 512->64 nodes, dl packed into src word
//   (tmp_d deleted), new binB2 does per-bucket src-block counting sort.
//   spmm2 / gemm1 / gemm2 unchanged.
// ---------------------------------------------------------------------------

#define NFEAT 512
#define NHID  256
#define NCLASS 40
#define BKT_SHIFT 6
#define BKT_NODES 64
#define MAX_BKT 2048     // >= ceil(100000/64)=1563
#define SRC_SHIFT 12     // src-block = 4096 nodes = 2MB of support1
#define BIN_EPB 4096     // edges per binA block

typedef __attribute__((ext_vector_type(4))) float f32x4;
typedef __attribute__((ext_vector_type(8))) short s16x8;

__device__ __forceinline__ ushort f2bf(float f) {
  unsigned u = __float_as_uint(f);
  u = (u + 0x7fffu + ((u >> 16) & 1u)) >> 16;  // RNE
  return (ushort)u;
}
__device__ __forceinline__ float bflo(unsigned u) {
  return __uint_as_float(u << 16);
}
__device__ __forceinline__ float bfhi(unsigned u) {
  return __uint_as_float(u & 0xffff0000u);
}

// -------------------- W1 transpose+convert: [512][256] -> bf16 [256][512] --
__global__ __launch_bounds__(256) void w1t_kernel(const float* __restrict__ W1,
                                                  ushort* __restrict__ Bt) {
  int idx = blockIdx.x * 256 + threadIdx.x;
  int k = idx >> 8, n = idx & 255;
  Bt[n * NFEAT + k] = f2bf(W1[idx]);
}

// ------------------------- GEMM1: bf16 MFMA -------------------------------
#define LDK 40  // padded LDS k-stride (bf16): max 2-way bank aliasing (free)
__global__ __launch_bounds__(256) void gemm1_mfma(
    const float* __restrict__ A, const ushort* __restrict__ Bt,
    ushort* __restrict__ C, int M) {
  __shared__ ushort As[128 * LDK];
  __shared__ ushort Bs[128 * LDK];
  int tid = threadIdx.x;
  int wave = tid >> 6, lane = tid & 63;
  int bm = blockIdx.y * 128;
  int bn = blockIdx.x * 128;
  int wm = (wave & 1) * 64, wn = (wave >> 1) * 64;
  int lm = lane & 15;
  int lk = (lane >> 4) * 8;

  int arow = tid >> 1;
  int ahalf = (tid & 1) * 16;
  int brow = tid >> 2;
  int bq = (tid & 3) * 8;

  f32x4 acc[4][4] = {};

  const bool arv = (bm + arow) < M;
  const float* aptr = A + (size_t)(bm + arow) * NFEAT + ahalf;
  ushort* asp = &As[arow * LDK + ahalf];

  for (int k0 = 0; k0 < NFEAT; k0 += 32) {
#pragma unroll
    for (int q = 0; q < 4; ++q) {
      float4 v = arv ? *(const float4*)(aptr + k0 + q * 4)
                     : make_float4(0.f, 0.f, 0.f, 0.f);
      ushort4 b;
      b.x = f2bf(v.x); b.y = f2bf(v.y); b.z = f2bf(v.z); b.w = f2bf(v.w);
      *(ushort4*)(asp + q * 4) = b;
    }
#pragma unroll
    for (int p = 0; p < 2; ++p) {
      int n = p * 64 + brow;
      *(uint4*)&Bs[n * LDK + bq] =
          *(const uint4*)&Bt[(size_t)(bn + n) * NFEAT + k0 + bq];
    }
    __syncthreads();
    s16x8 afr[4], bfr[4];
#pragma unroll
    for (int i = 0; i < 4; ++i)
      afr[i] = *(const s16x8*)&As[(wm + i * 16 + lm) * LDK + lk];
#pragma unroll
    for (int j = 0; j < 4; ++j)
      bfr[j] = *(const s16x8*)&Bs[(wn + j * 16 + lm) * LDK + lk];
#pragma unroll
    for (int i = 0; i < 4; ++i)
#pragma unroll
      for (int j = 0; j < 4; ++j)
        acc[i][j] = __builtin_amdgcn_mfma_f32_16x16x32_bf16(afr[i], bfr[j],
                                                            acc[i][j], 0, 0, 0);
    __syncthreads();
  }
  int ocol = bn + wn + lm;
  int orow0 = bm + wm + (lane >> 4) * 4;
#pragma unroll
  for (int i = 0; i < 4; ++i) {
#pragma unroll
    for (int r = 0; r < 4; ++r) {
      int row = orow0 + i * 16 + r;
      if (row < M) {
#pragma unroll
        for (int j = 0; j < 4; ++j)
          C[(size_t)row * NHID + ocol + j * 16] = f2bf(acc[i][j][r]);
      }
    }
  }
}

// ------------------------- CSR build --------------------------------------
__global__ __launch_bounds__(256) void hist_kernel(const int* __restrict__ dst,
                                                   int* __restrict__ deg, int E) {
  int e = blockIdx.x * 256 + threadIdx.x;
  if (e < E) atomicAdd(&deg[dst[e]], 1);
}

__global__ __launch_bounds__(256) void scan1_kernel(const int* __restrict__ deg,
                                                    int* __restrict__ part,
                                                    int* __restrict__ bsums, int M) {
  __shared__ int tmp[256];
  int t = threadIdx.x;
  int i = blockIdx.x * 256 + t;
  int v = (i < M) ? deg[i] : 0;
  tmp[t] = v;
  __syncthreads();
  for (int off = 1; off < 256; off <<= 1) {
    int add = (t >= off) ? tmp[t - off] : 0;
    __syncthreads();
    tmp[t] += add;
    __syncthreads();
  }
  if (i < M) part[i] = tmp[t];
  if (t == 255) bsums[blockIdx.x] = tmp[255];
}

__global__ __launch_bounds__(512) void scan2_kernel(int* __restrict__ bsums, int nb) {
  __shared__ int tmp[512];
  int t = threadIdx.x;
  int v = (t < nb) ? bsums[t] : 0;
  tmp[t] = v;
  __syncthreads();
  for (int off = 1; off < 512; off <<= 1) {
    int add = (t >= off) ? tmp[t - off] : 0;
    __syncthreads();
    tmp[t] += add;
    __syncthreads();
  }
  if (t < nb) bsums[t] = tmp[t];
}

__global__ __launch_bounds__(256) void scan3_kernel(
    const int* __restrict__ part, const int* __restrict__ bsums,
    const int* __restrict__ deg, int* __restrict__ rowptr, int M) {
  int i = blockIdx.x * 256 + threadIdx.x;
  if (i >= M) return;
  int incl = part[i] + (blockIdx.x > 0 ? bsums[blockIdx.x - 1] : 0);
  rowptr[i] = incl - deg[i];
}

// bucket cursors: gcursor[b] = rowptr[b*64]
__global__ __launch_bounds__(256) void initcur_kernel(
    const int* __restrict__ rowptr, int* __restrict__ gcursor, int nbkt) {
  int b = blockIdx.x * 256 + threadIdx.x;
  if (b < nbkt) gcursor[b] = rowptr[b * BKT_NODES];
}

// binA: bucket-major binning. Per-block LDS histogram -> one global reserve
// per (block,bucket) -> write packed ((dl6<<17)|src, w) int2 into tmp.
__global__ __launch_bounds__(256) void binA_kernel(
    const int* __restrict__ esrc, const int* __restrict__ edst,
    const float* __restrict__ ew, int* __restrict__ gcursor,
    int2* __restrict__ tmp_sw, int E, int nbkt) {
  __shared__ int hist[MAX_BKT];
  int t = threadIdx.x;
  for (int i = t; i < nbkt; i += 256) hist[i] = 0;
  __syncthreads();
  int e0 = blockIdx.x * BIN_EPB;
#pragma unroll
  for (int k = 0; k < BIN_EPB / 256; ++k) {
    int e = e0 + k * 256 + t;
    if (e < E) atomicAdd(&hist[edst[e] >> BKT_SHIFT], 1);
  }
  __syncthreads();
  // reserve: hist[b] becomes this block's running cursor (global base)
  for (int i = t; i < nbkt; i += 256) {
    int c = hist[i];
    hist[i] = c ? atomicAdd(&gcursor[i], c) : 0;
  }
  __syncthreads();
#pragma unroll
  for (int k = 0; k < BIN_EPB / 256; ++k) {
    int e = e0 + k * 256 + t;
    if (e < E) {
      int d = edst[e];
      int b = d >> BKT_SHIFT;
      int pos = atomicAdd(&hist[b], 1);
      tmp_sw[pos] = make_int2(((d & (BKT_NODES - 1)) << 17) | esrc[e],
                              __float_as_int(ew[e]));
    }
  }
}

// binB: per-node CSR order (for spmm2). One block per 64-node bucket;
// LDS per-node cursors; unpacks (src, w) into ep.
__global__ __launch_bounds__(256) void binB_kernel(
    const int2* __restrict__ tmp_sw, const int* __restrict__ rowptr,
    int2* __restrict__ ep, int M, int E) {
  __shared__ int cur[BKT_NODES];
  int tid = threadIdx.x;
  int nbase = blockIdx.x << BKT_SHIFT;
  if (tid < BKT_NODES) {
    int node = nbase + tid;
    cur[tid] = (node < M) ? rowptr[node] : 0;
  }
  __syncthreads();
  int s = rowptr[nbase];
  int nend = nbase + BKT_NODES;
  int e = (nend < M) ? rowptr[nend] : E;
  for (int i = s + tid; i < e; i += 256) {
    int2 r = tmp_sw[i];
    int dl = r.x >> 17;
    int pos = atomicAdd(&cur[dl], 1);
    ep[pos] = make_int2(r.x & 0x1FFFF, r.y);
  }
}

// binB2: per-bucket counting sort by src-block (src>>12, <=25 bins) -> ep2
// (packed form retained). Gives the in-phase src sweep for spmm1_lds.
__global__ __launch_bounds__(256) void binB2_kernel(
    const int2* __restrict__ tmp_sw, const int* __restrict__ rowptr,
    int2* __restrict__ ep2, int M, int E) {
  __shared__ int h2[32];
  __shared__ int c2[32];
  int tid = threadIdx.x;
  int nbase = blockIdx.x << BKT_SHIFT;
  if (tid < 32) h2[tid] = 0;
  __syncthreads();
  int s = rowptr[nbase];
  int nend = nbase + BKT_NODES;
  int e = (nend < M) ? rowptr[nend] : E;
  for (int i = s + tid; i < e; i += 256) {
    int blk = (tmp_sw[i].x & 0x1FFFF) >> SRC_SHIFT;
    atomicAdd(&h2[blk], 1);
  }
  __syncthreads();
  if (tid == 0) {
    int run = s;
#pragma unroll
    for (int k = 0; k < 32; ++k) {
      int c = h2[k];
      c2[k] = run;
      run += c;
    }
  }
  __syncthreads();
  for (int i = s + tid; i < e; i += 256) {
    int2 r = tmp_sw[i];
    int blk = (r.x & 0x1FFFF) >> SRC_SHIFT;
    int pos = atomicAdd(&c2[blk], 1);
    ep2[pos] = r;
  }
}

// ---------------- SpMM1: src-blocked LDS-accumulator + ReLU ---------------
// One block per 64-dst bucket. acc[64][256] f32 = 64KB LDS (2 blocks/CU).
// Wave w owns feats [64w,64w+64) -> no cross-wave races. Per step, lanes
// 0-31 handle edge i (feats 2p,2p+1 via one uint gather), lanes 32-63 edge
// i+1. LDS atomicAdd f32; lower half adds even-feat first, upper half
// odd-first -> each atomic instr is 2 lanes/bank (conflict-free).
__global__ __launch_bounds__(256) void spmm1_lds_kernel(
    const ushort* __restrict__ S, const int* __restrict__ rowptr,
    const int2* __restrict__ ep2, const float* __restrict__ b1,
    ushort* __restrict__ h, int M, int E) {
  __shared__ __align__(16) float acc[BKT_NODES * NHID];  // 65536 B
  int tid = threadIdx.x;
  int w = tid >> 6;
  int lane = tid & 63;
  int half = lane >> 5;
  int p = lane & 31;
  f32x4 z = {0.f, 0.f, 0.f, 0.f};
  for (int i = tid; i < BKT_NODES * NHID / 4; i += 256) ((f32x4*)acc)[i] = z;
  __syncthreads();
  int nbase = blockIdx.x << BKT_SHIFT;
  int s = rowptr[nbase];
  int nend = nbase + BKT_NODES;
  int e = (nend < M) ? rowptr[nend] : E;
  const unsigned* Sw = (const unsigned*)S;  // 4B = 2 bf16 feats
  int foff = (w << 6) + 2 * p;              // feat base within 256
  int gcol = (w << 5) + p;                  // uint column within row (128)
  for (int i0 = s; i0 < e; i0 += 8) {
#pragma unroll
    for (int u = 0; u < 4; ++u) {
      int idx = i0 + 2 * u + half;
      int2 r = (idx < e) ? ep2[idx] : make_int2(0, 0);
      int src = r.x & 0x1FFFF;
      int dl = r.x >> 17;
      float wgt = __int_as_float(r.y);
      unsigned g = Sw[(size_t)src * 128 + gcol];
      float v0 = wgt * bflo(g);
      float v1 = wgt * bfhi(g);
      float* a = &acc[dl * NHID + foff];
      // bank-parity ordering: lower half even-first, upper half odd-first
      atomicAdd(&a[half], half ? v1 : v0);
      atomicAdd(&a[1 - half], half ? v0 : v1);
    }
  }
  __syncthreads();
  // writeout: bias + relu + bf16 pack, coalesced uint stores
  for (int i = tid; i < BKT_NODES * 128; i += 256) {
    int dl = i >> 7;
    int pp = i & 127;
    int node = nbase + dl;
    if (node < M) {
      float2 v = *(float2*)&acc[dl * NHID + pp * 2];
      float2 bb = *(const float2*)(b1 + pp * 2);
      float r0 = fmaxf(v.x + bb.x, 0.f);
      float r1 = fmaxf(v.y + bb.y, 0.f);
      unsigned o = (unsigned)f2bf(r0) | ((unsigned)f2bf(r1) << 16);
      ((unsigned*)h)[(size_t)node * 128 + pp] = o;
    }
  }
}

// ------------------- GEMM2: h(bf16) @ W2 -> bf16, W2 in LDS ---------------
__global__ __launch_bounds__(256) void gemm2_kernel(
    const ushort* __restrict__ H, const float* __restrict__ W2,
    ushort* __restrict__ S2, int M) {
  __shared__ float W2s[NHID * NCLASS];
  for (int i = threadIdx.x; i < NHID * NCLASS; i += 256) W2s[i] = W2[i];
  __syncthreads();
  int row = blockIdx.x * 256 + threadIdx.x;
  if (row >= M) return;
  const float4* W2v = (const float4*)W2s;
  float4 acc[10];
#pragma unroll
  for (int j = 0; j < 10; ++j) acc[j] = make_float4(0.f, 0.f, 0.f, 0.f);
  const uint4* hp = (const uint4*)(H + (size_t)row * NHID);
  for (int kb = 0; kb < 32; ++kb) {
    uint4 u = hp[kb];
    float a[8] = {bflo(u.x), bfhi(u.x), bflo(u.y), bfhi(u.y),
                  bflo(u.z), bfhi(u.z), bflo(u.w), bfhi(u.w)};
#pragma unroll
    for (int kk = 0; kk < 8; ++kk) {
#pragma unroll
      for (int j = 0; j < 10; ++j) {
        float4 wv = W2v[(kb * 8 + kk) * 10 + j];
        acc[j].x += a[kk] * wv.x;
        acc[j].y += a[kk] * wv.y;
        acc[j].z += a[kk] * wv.z;
        acc[j].w += a[kk] * wv.w;
      }
    }
  }
  uint2* outp = (uint2*)(S2 + (size_t)row * NCLASS);
#pragma unroll
  for (int j = 0; j < 10; j += 2) {
    uint2 o0, o1;
    o0.x = (unsigned)f2bf(acc[j].x) | ((unsigned)f2bf(acc[j].y) << 16);
    o0.y = (unsigned)f2bf(acc[j].z) | ((unsigned)f2bf(acc[j].w) << 16);
    o1.x = (unsigned)f2bf(acc[j + 1].x) | ((unsigned)f2bf(acc[j + 1].y) << 16);
    o1.y = (unsigned)f2bf(acc[j + 1].z) | ((unsigned)f2bf(acc[j + 1].w) << 16);
    outp[j] = o0;
    outp[j + 1] = o1;
  }
}

// -------- SpMM2 (CSR, bf16) + bias + log_softmax, one wave per node -------
// 3 edge-groups of 20 lanes (lanes 60-63 idle), each lane owns 2 classes.
// x2 unroll -> 6 edges / 2 loads in flight. Cross-group reduce via shfl.
__global__ __launch_bounds__(256) void spmm2_csr_kernel(
    const ushort* __restrict__ S2, const int* __restrict__ rowptr,
    const int* __restrict__ deg, const int2* __restrict__ ep,
    const float* __restrict__ b2, float* __restrict__ out, int M) {
  int wid = (blockIdx.x * 256 + threadIdx.x) >> 6;
  int lane = threadIdx.x & 63;
  if (wid >= M) return;
  int beg = rowptr[wid];
  int n = deg[wid];
  int g = (lane >= 40) ? 2 : ((lane >= 20) ? 1 : 0);
  bool act = lane < 60;
  int cl = lane - 20 * g;                 // class pair 0..19
  const ushort* S2l = S2 + cl * 2;
  float acc0 = 0.f, acc1 = 0.f;
  for (int j0 = 0; j0 < n; j0 += 64) {
    int cnt = min(64, n - j0);
    int msrc = 0;
    float mw = 0.f;
    if (lane < cnt) {
      int2 e = ep[beg + j0 + lane];
      msrc = e.x;
      mw = __int_as_float(e.y);
    }
    int trips = (cnt + 2) / 3;  // <= 22
    for (int p = 0; p < trips; p += 2) {
      int ja = 3 * p + g;
      int jb = ja + 3;
      int sa = __shfl(msrc, ja & 63); float wa = __shfl(mw, ja & 63);
      int sb = __shfl(msrc, jb & 63); float wb = __shfl(mw, jb & 63);
      wa = (act && ja < cnt) ? wa : 0.f;
      wb = (act && jb < cnt) ? wb : 0.f;
      unsigned ua = *(const unsigned*)(S2l + (size_t)sa * NCLASS);
      unsigned ub = *(const unsigned*)(S2l + (size_t)sb * NCLASS);
      acc0 += wa * bflo(ua) + wb * bflo(ub);
      acc1 += wa * bfhi(ua) + wb * bfhi(ub);
    }
  }
  // reduce the 3 groups: totals land in lanes 0..19
  float r0a = __shfl(acc0, (lane + 20) & 63);
  float r0b = __shfl(acc0, (lane + 40) & 63);
  float r1a = __shfl(acc1, (lane + 20) & 63);
  float r1b = __shfl(acc1, (lane + 40) & 63);
  float v0 = -INFINITY, v1 = -INFINITY;
  if (lane < 20) {
    float2 b = *(const float2*)(b2 + lane * 2);
    v0 = acc0 + r0a + r0b + b.x;
    v1 = acc1 + r1a + r1b + b.y;
  }
  float m = fmaxf(v0, v1);
#pragma unroll
  for (int off = 32; off; off >>= 1) m = fmaxf(m, __shfl_xor(m, off));
  float ex = (lane < 20) ? __expf(v0 - m) + __expf(v1 - m) : 0.f;
  float s = ex;
#pragma unroll
  for (int off = 32; off; off >>= 1) s += __shfl_xor(s, off);
  float lse = m + __logf(s);
  if (lane < 20) {
    float2 o = {v0 - lse, v1 - lse};
    *(float2*)(out + (size_t)wid * NCLASS + lane * 2) = o;
  }
}

// ---------------------------------------------------------------------------
extern "C" void kernel_launch(void* const* d_in, const int* in_sizes, int n_in,
                              void* d_out, int out_size, void* d_ws,
                              size_t ws_size, hipStream_t stream) {
  const float* x  = (const float*)d_in[0];
  const int* esrc = (const int*)d_in[1];
  const int* edst = (const int*)d_in[2];
  const float* ew = (const float*)d_in[3];
  const float* W1 = (const float*)d_in[4];
  const float* b1 = (const float*)d_in[5];
  const float* W2 = (const float*)d_in[6];
  const float* b2 = (const float*)d_in[7];
  float* out = (float*)d_out;

  const int M = in_sizes[0] / NFEAT;  // 100000
  const int E = in_sizes[1];          // 3200000
  const int nbkt = (M + BKT_NODES - 1) / BKT_NODES;  // 1563

  char* p = (char*)d_ws;
  ushort* support1 = (ushort*)p;           p += (size_t)M * NHID * 2;
  ushort* h        = (ushort*)p;           p += (size_t)M * NHID * 2;
  ushort* support2 = (ushort*)p;           p += (size_t)M * NCLASS * 2;
  ushort* W1t      = (ushort*)p;           p += (size_t)NFEAT * NHID * 2;
  int*    deg      = (int*)p;              p += (size_t)M * 4;
  int*    part     = (int*)p;              p += (size_t)M * 4;
  int*    rowptr   = (int*)p;              p += (size_t)M * 4;
  int*    gcursor  = (int*)p;              p += MAX_BKT * 4;
  int*    bsums    = (int*)p;              p += 512 * 4;
  int2*   ep       = (int2*)p;             p += (size_t)E * 8;
  int2*   tmp_sw   = (int2*)p;             p += (size_t)E * 8;
  int2*   ep2      = (int2*)p;             // E * 8

  const int nbScan = (M + 255) / 256;  // 391 <= 512

  // ---- CSR build: hist -> rowptr -> bucketed counting sorts ----
  hipMemsetAsync(deg, 0, (size_t)M * sizeof(int), stream);
  hist_kernel<<<(E + 255) / 256, 256, 0, stream>>>(edst, deg, E);
  scan1_kernel<<<nbScan, 256, 0, stream>>>(deg, part, bsums, M);
  scan2_kernel<<<1, 512, 0, stream>>>(bsums, nbScan);
  scan3_kernel<<<nbScan, 256, 0, stream>>>(part, bsums, deg, rowptr, M);
  initcur_kernel<<<(nbkt + 255) / 256, 256, 0, stream>>>(rowptr, gcursor, nbkt);
  binA_kernel<<<(E + BIN_EPB - 1) / BIN_EPB, 256, 0, stream>>>(
      esrc, edst, ew, gcursor, tmp_sw, E, nbkt);
  binB_kernel<<<nbkt, 256, 0, stream>>>(tmp_sw, rowptr, ep, M, E);
  binB2_kernel<<<nbkt, 256, 0, stream>>>(tmp_sw, rowptr, ep2, M, E);

  // ---- layer 1 ----
  w1t_kernel<<<(NFEAT * NHID) / 256, 256, 0, stream>>>(W1, W1t);
  dim3 g1(NHID / 128, (M + 127) / 128);
  gemm1_mfma<<<g1, 256, 0, stream>>>(x, W1t, support1, M);
  spmm1_lds_kernel<<<nbkt, 256, 0, stream>>>(support1, rowptr, ep2, b1, h, M, E);

  // ---- layer 2 ----
  gemm2_kernel<<<(M + 255) / 256, 256, 0, stream>>>(h, W2, support2, M);
  spmm2_csr_kernel<<<(M * 64 + 255) / 256, 256, 0, stream>>>(
      support2, rowptr, deg, ep, b2, out, M);
}

// Round 4
// 1127.940 us; speedup vs baseline: 4.7857x; 4.7857x over previous
//
#include <hip/hip_runtime.h>
#include <hip/hip_bf16.h>
#include <math.h>

// ---------------------------------------------------------------------------
// GCN 2-layer forward, bf16 MFMA GEMM1 + bf16 activations.
// R8: spmm1 = src-phased bucket aggregation WITHOUT atomics.
//   R7 evidence: LDS fp atomicAdd compiled to a CAS loop (VALUBusy 4.4%,
//   20x slowdown) but phasing worked (FETCH 755->607MB) and the CSR sort
//   machinery verified correct. v3 mechanism: 256 threads <-> 256 feature
//   columns, exclusive ownership -> plain LDS RMW, race-free by
//   construction. Bucket 32 dst nodes (32KB acc -> 4 blocks/CU, 4 waves/
//   SIMD hide the RMW latency chain). Edge records double-buffered in LDS,
//   wave-uniform broadcast reads. Edges sorted (bucket, src>>12) by
//   verified binA/binB2 so all CUs sweep 2MB support slices in phase.
// ---------------------------------------------------------------------------

#define NFEAT 512
#define NHID  256
#define NCLASS 40
#define BKT_SHIFT 5
#define BKT_NODES 32
#define MAX_BKT 3328     // >= ceil(100000/32)=3125, multiple of 256
#define SRC_SHIFT 12     // src-block = 4096 nodes = 2MB of support1
#define BIN_EPB 8192     // edges per binA block

typedef __attribute__((ext_vector_type(4))) float f32x4;
typedef __attribute__((ext_vector_type(8))) short s16x8;

__device__ __forceinline__ ushort f2bf(float f) {
  unsigned u = __float_as_uint(f);
  u = (u + 0x7fffu + ((u >> 16) & 1u)) >> 16;  // RNE
  return (ushort)u;
}
__device__ __forceinline__ float bflo(unsigned u) {
  return __uint_as_float(u << 16);
}
__device__ __forceinline__ float bfhi(unsigned u) {
  return __uint_as_float(u & 0xffff0000u);
}

// -------------------- W1 transpose+convert: [512][256] -> bf16 [256][512] --
__global__ __launch_bounds__(256) void w1t_kernel(const float* __restrict__ W1,
                                                  ushort* __restrict__ Bt) {
  int idx = blockIdx.x * 256 + threadIdx.x;
  int k = idx >> 8, n = idx & 255;
  Bt[n * NFEAT + k] = f2bf(W1[idx]);
}

// ------------------------- GEMM1: bf16 MFMA -------------------------------
#define LDK 40  // padded LDS k-stride (bf16): max 2-way bank aliasing (free)
__global__ __launch_bounds__(256) void gemm1_mfma(
    const float* __restrict__ A, const ushort* __restrict__ Bt,
    ushort* __restrict__ C, int M) {
  __shared__ ushort As[128 * LDK];
  __shared__ ushort Bs[128 * LDK];
  int tid = threadIdx.x;
  int wave = tid >> 6, lane = tid & 63;
  int bm = blockIdx.y * 128;
  int bn = blockIdx.x * 128;
  int wm = (wave & 1) * 64, wn = (wave >> 1) * 64;
  int lm = lane & 15;
  int lk = (lane >> 4) * 8;

  int arow = tid >> 1;
  int ahalf = (tid & 1) * 16;
  int brow = tid >> 2;
  int bq = (tid & 3) * 8;

  f32x4 acc[4][4] = {};

  const bool arv = (bm + arow) < M;
  const float* aptr = A + (size_t)(bm + arow) * NFEAT + ahalf;
  ushort* asp = &As[arow * LDK + ahalf];

  for (int k0 = 0; k0 < NFEAT; k0 += 32) {
#pragma unroll
    for (int q = 0; q < 4; ++q) {
      float4 v = arv ? *(const float4*)(aptr + k0 + q * 4)
                     : make_float4(0.f, 0.f, 0.f, 0.f);
      ushort4 b;
      b.x = f2bf(v.x); b.y = f2bf(v.y); b.z = f2bf(v.z); b.w = f2bf(v.w);
      *(ushort4*)(asp + q * 4) = b;
    }
#pragma unroll
    for (int p = 0; p < 2; ++p) {
      int n = p * 64 + brow;
      *(uint4*)&Bs[n * LDK + bq] =
          *(const uint4*)&Bt[(size_t)(bn + n) * NFEAT + k0 + bq];
    }
    __syncthreads();
    s16x8 afr[4], bfr[4];
#pragma unroll
    for (int i = 0; i < 4; ++i)
      afr[i] = *(const s16x8*)&As[(wm + i * 16 + lm) * LDK + lk];
#pragma unroll
    for (int j = 0; j < 4; ++j)
      bfr[j] = *(const s16x8*)&Bs[(wn + j * 16 + lm) * LDK + lk];
#pragma unroll
    for (int i = 0; i < 4; ++i)
#pragma unroll
      for (int j = 0; j < 4; ++j)
        acc[i][j] = __builtin_amdgcn_mfma_f32_16x16x32_bf16(afr[i], bfr[j],
                                                            acc[i][j], 0, 0, 0);
    __syncthreads();
  }
  int ocol = bn + wn + lm;
  int orow0 = bm + wm + (lane >> 4) * 4;
#pragma unroll
  for (int i = 0; i < 4; ++i) {
#pragma unroll
    for (int r = 0; r < 4; ++r) {
      int row = orow0 + i * 16 + r;
      if (row < M) {
#pragma unroll
        for (int j = 0; j < 4; ++j)
          C[(size_t)row * NHID + ocol + j * 16] = f2bf(acc[i][j][r]);
      }
    }
  }
}

// ------------------------- CSR build --------------------------------------
__global__ __launch_bounds__(256) void hist_kernel(const int* __restrict__ dst,
                                                   int* __restrict__ deg, int E) {
  int e = blockIdx.x * 256 + threadIdx.x;
  if (e < E) atomicAdd(&deg[dst[e]], 1);
}

__global__ __launch_bounds__(256) void scan1_kernel(const int* __restrict__ deg,
                                                    int* __restrict__ part,
                                                    int* __restrict__ bsums, int M) {
  __shared__ int tmp[256];
  int t = threadIdx.x;
  int i = blockIdx.x * 256 + t;
  int v = (i < M) ? deg[i] : 0;
  tmp[t] = v;
  __syncthreads();
  for (int off = 1; off < 256; off <<= 1) {
    int add = (t >= off) ? tmp[t - off] : 0;
    __syncthreads();
    tmp[t] += add;
    __syncthreads();
  }
  if (i < M) part[i] = tmp[t];
  if (t == 255) bsums[blockIdx.x] = tmp[255];
}

__global__ __launch_bounds__(512) void scan2_kernel(int* __restrict__ bsums, int nb) {
  __shared__ int tmp[512];
  int t = threadIdx.x;
  int v = (t < nb) ? bsums[t] : 0;
  tmp[t] = v;
  __syncthreads();
  for (int off = 1; off < 512; off <<= 1) {
    int add = (t >= off) ? tmp[t - off] : 0;
    __syncthreads();
    tmp[t] += add;
    __syncthreads();
  }
  if (t < nb) bsums[t] = tmp[t];
}

__global__ __launch_bounds__(256) void scan3_kernel(
    const int* __restrict__ part, const int* __restrict__ bsums,
    const int* __restrict__ deg, int* __restrict__ rowptr, int M) {
  int i = blockIdx.x * 256 + threadIdx.x;
  if (i >= M) return;
  int incl = part[i] + (blockIdx.x > 0 ? bsums[blockIdx.x - 1] : 0);
  rowptr[i] = incl - deg[i];
}

// bucket cursors: gcursor[b] = rowptr[b*32]
__global__ __launch_bounds__(256) void initcur_kernel(
    const int* __restrict__ rowptr, int* __restrict__ gcursor, int nbkt) {
  int b = blockIdx.x * 256 + threadIdx.x;
  if (b < nbkt) gcursor[b] = rowptr[b * BKT_NODES];
}

// binA: bucket-major binning. Per-block LDS histogram -> one global reserve
// per (block,bucket) -> write packed ((dl5<<17)|src, w) int2 into tmp.
__global__ __launch_bounds__(256) void binA_kernel(
    const int* __restrict__ esrc, const int* __restrict__ edst,
    const float* __restrict__ ew, int* __restrict__ gcursor,
    int2* __restrict__ tmp_sw, int E, int nbkt) {
  __shared__ int hist[MAX_BKT];
  int t = threadIdx.x;
  for (int i = t; i < nbkt; i += 256) hist[i] = 0;
  __syncthreads();
  int e0 = blockIdx.x * BIN_EPB;
#pragma unroll
  for (int k = 0; k < BIN_EPB / 256; ++k) {
    int e = e0 + k * 256 + t;
    if (e < E) atomicAdd(&hist[edst[e] >> BKT_SHIFT], 1);
  }
  __syncthreads();
  // reserve: hist[b] becomes this block's running cursor (global base)
  for (int i = t; i < nbkt; i += 256) {
    int c = hist[i];
    hist[i] = c ? atomicAdd(&gcursor[i], c) : 0;
  }
  __syncthreads();
#pragma unroll
  for (int k = 0; k < BIN_EPB / 256; ++k) {
    int e = e0 + k * 256 + t;
    if (e < E) {
      int d = edst[e];
      int b = d >> BKT_SHIFT;
      int pos = atomicAdd(&hist[b], 1);
      tmp_sw[pos] = make_int2(((d & (BKT_NODES - 1)) << 17) | esrc[e],
                              __float_as_int(ew[e]));
    }
  }
}

// binB: per-node CSR order (for spmm2). One block per 32-node bucket;
// LDS per-node cursors; unpacks (src, w) into ep.
__global__ __launch_bounds__(256) void binB_kernel(
    const int2* __restrict__ tmp_sw, const int* __restrict__ rowptr,
    int2* __restrict__ ep, int M, int E) {
  __shared__ int cur[BKT_NODES];
  int tid = threadIdx.x;
  int nbase = blockIdx.x << BKT_SHIFT;
  if (tid < BKT_NODES) {
    int node = nbase + tid;
    cur[tid] = (node < M) ? rowptr[node] : 0;
  }
  __syncthreads();
  int s = rowptr[nbase];
  int nend = nbase + BKT_NODES;
  int e = (nend < M) ? rowptr[nend] : E;
  for (int i = s + tid; i < e; i += 256) {
    int2 r = tmp_sw[i];
    int dl = r.x >> 17;
    int pos = atomicAdd(&cur[dl], 1);
    ep[pos] = make_int2(r.x & 0x1FFFF, r.y);
  }
}

// binB2: per-bucket counting sort by src-block (src>>12, <=25 bins) -> ep2
// (packed form retained). Gives the in-phase src sweep for spmm1_lds.
__global__ __launch_bounds__(256) void binB2_kernel(
    const int2* __restrict__ tmp_sw, const int* __restrict__ rowptr,
    int2* __restrict__ ep2, int M, int E) {
  __shared__ int h2[32];
  __shared__ int c2[32];
  int tid = threadIdx.x;
  int nbase = blockIdx.x << BKT_SHIFT;
  if (tid < 32) h2[tid] = 0;
  __syncthreads();
  int s = rowptr[nbase];
  int nend = nbase + BKT_NODES;
  int e = (nend < M) ? rowptr[nend] : E;
  for (int i = s + tid; i < e; i += 256) {
    int blk = (tmp_sw[i].x & 0x1FFFF) >> SRC_SHIFT;
    atomicAdd(&h2[blk], 1);
  }
  __syncthreads();
  if (tid == 0) {
    int run = s;
#pragma unroll
    for (int k = 0; k < 32; ++k) {
      int c = h2[k];
      c2[k] = run;
      run += c;
    }
  }
  __syncthreads();
  for (int i = s + tid; i < e; i += 256) {
    int2 r = tmp_sw[i];
    int blk = (r.x & 0x1FFFF) >> SRC_SHIFT;
    int pos = atomicAdd(&c2[blk], 1);
    ep2[pos] = r;
  }
}

// ---------------- SpMM1: src-phased bucket aggregation, NO atomics --------
// One block per 32-dst bucket. acc[32][256] f32 = 32KB LDS (4 blocks/CU).
// Thread tid owns feature column tid EXCLUSIVELY: acc[dl*256+tid] is only
// ever touched by this thread -> plain LDS read-modify-write is race-free.
// All threads process every edge; wave w gathers 128 contiguous bytes
// (feats [64w,64w+64)) of the src row. Edge records double-buffered in LDS
// (one sync per 64-edge chunk), read via wave-uniform broadcast ds_read.
__global__ __launch_bounds__(256) void spmm1_lds_kernel(
    const ushort* __restrict__ S, const int* __restrict__ rowptr,
    const int2* __restrict__ ep2, const float* __restrict__ b1,
    ushort* __restrict__ h, int M, int E) {
  __shared__ __align__(16) float acc[BKT_NODES * NHID];  // 32768 B
  __shared__ int2 eb[2][64];
  int tid = threadIdx.x;
  f32x4 z = {0.f, 0.f, 0.f, 0.f};
  for (int i = tid; i < BKT_NODES * NHID / 4; i += 256) ((f32x4*)acc)[i] = z;
  int nbase = blockIdx.x << BKT_SHIFT;
  int s = rowptr[nbase];
  int nend = nbase + BKT_NODES;
  int e = (nend < M) ? rowptr[nend] : E;
  const ushort* Sf = S + tid;  // this thread's feature column
  float* af = acc + tid;
  if (tid < 64) {
    int idx = s + tid;
    eb[0][tid] = (idx < e) ? ep2[idx] : make_int2(0, 0);
  }
  __syncthreads();
  int nch = (e - s + 63) >> 6;
  for (int c = 0; c < nch; ++c) {
    if (tid < 64 && (c + 1) < nch) {
      int idx = s + (c + 1) * 64 + tid;
      eb[(c + 1) & 1][tid] = (idx < e) ? ep2[idx] : make_int2(0, 0);
    }
    const int2* ecur = eb[c & 1];
#pragma unroll 8
    for (int j = 0; j < 64; ++j) {
      int2 r = ecur[j];                     // wave-uniform broadcast
      int sr = r.x & 0x1FFFF;
      int dl = r.x >> 17;
      float wgt = __int_as_float(r.y);      // 0.0 for pad entries
      float v = bflo(Sf[(size_t)sr << 8]);  // 2B gather, 128B/wave coalesced
      af[dl << 8] += wgt * v;               // exclusive-column LDS RMW
    }
    __syncthreads();  // next buffer staged + everyone done before overwrite
  }
  // writeout: bias + relu + bf16 pack, coalesced uint stores
  for (int i = tid; i < BKT_NODES * 128; i += 256) {
    int dl = i >> 7;
    int pp = i & 127;
    int node = nbase + dl;
    if (node < M) {
      float2 vv = *(float2*)&acc[(dl << 8) + pp * 2];
      float2 bb = *(const float2*)(b1 + pp * 2);
      unsigned o = (unsigned)f2bf(fmaxf(vv.x + bb.x, 0.f)) |
                   ((unsigned)f2bf(fmaxf(vv.y + bb.y, 0.f)) << 16);
      ((unsigned*)h)[(size_t)node * 128 + pp] = o;
    }
  }
}

// ------------------- GEMM2: h(bf16) @ W2 -> bf16, W2 in LDS ---------------
__global__ __launch_bounds__(256) void gemm2_kernel(
    const ushort* __restrict__ H, const float* __restrict__ W2,
    ushort* __restrict__ S2, int M) {
  __shared__ float W2s[NHID * NCLASS];
  for (int i = threadIdx.x; i < NHID * NCLASS; i += 256) W2s[i] = W2[i];
  __syncthreads();
  int row = blockIdx.x * 256 + threadIdx.x;
  if (row >= M) return;
  const float4* W2v = (const float4*)W2s;
  float4 acc[10];
#pragma unroll
  for (int j = 0; j < 10; ++j) acc[j] = make_float4(0.f, 0.f, 0.f, 0.f);
  const uint4* hp = (const uint4*)(H + (size_t)row * NHID);
  for (int kb = 0; kb < 32; ++kb) {
    uint4 u = hp[kb];
    float a[8] = {bflo(u.x), bfhi(u.x), bflo(u.y), bfhi(u.y),
                  bflo(u.z), bfhi(u.z), bflo(u.w), bfhi(u.w)};
#pragma unroll
    for (int kk = 0; kk < 8; ++kk) {
#pragma unroll
      for (int j = 0; j < 10; ++j) {
        float4 wv = W2v[(kb * 8 + kk) * 10 + j];
        acc[j].x += a[kk] * wv.x;
        acc[j].y += a[kk] * wv.y;
        acc[j].z += a[kk] * wv.z;
        acc[j].w += a[kk] * wv.w;
      }
    }
  }
  uint2* outp = (uint2*)(S2 + (size_t)row * NCLASS);
#pragma unroll
  for (int j = 0; j < 10; j += 2) {
    uint2 o0, o1;
    o0.x = (unsigned)f2bf(acc[j].x) | ((unsigned)f2bf(acc[j].y) << 16);
    o0.y = (unsigned)f2bf(acc[j].z) | ((unsigned)f2bf(acc[j].w) << 16);
    o1.x = (unsigned)f2bf(acc[j + 1].x) | ((unsigned)f2bf(acc[j + 1].y) << 16);
    o1.y = (unsigned)f2bf(acc[j + 1].z) | ((unsigned)f2bf(acc[j + 1].w) << 16);
    outp[j] = o0;
    outp[j + 1] = o1;
  }
}

// -------- SpMM2 (CSR, bf16) + bias + log_softmax, one wave per node -------
// 3 edge-groups of 20 lanes (lanes 60-63 idle), each lane owns 2 classes.
// x2 unroll -> 6 edges / 2 loads in flight. Cross-group reduce via shfl.
__global__ __launch_bounds__(256) void spmm2_csr_kernel(
    const ushort* __restrict__ S2, const int* __restrict__ rowptr,
    const int* __restrict__ deg, const int2* __restrict__ ep,
    const float* __restrict__ b2, float* __restrict__ out, int M) {
  int wid = (blockIdx.x * 256 + threadIdx.x) >> 6;
  int lane = threadIdx.x & 63;
  if (wid >= M) return;
  int beg = rowptr[wid];
  int n = deg[wid];
  int g = (lane >= 40) ? 2 : ((lane >= 20) ? 1 : 0);
  bool act = lane < 60;
  int cl = lane - 20 * g;                 // class pair 0..19
  const ushort* S2l = S2 + cl * 2;
  float acc0 = 0.f, acc1 = 0.f;
  for (int j0 = 0; j0 < n; j0 += 64) {
    int cnt = min(64, n - j0);
    int msrc = 0;
    float mw = 0.f;
    if (lane < cnt) {
      int2 e = ep[beg + j0 + lane];
      msrc = e.x;
      mw = __int_as_float(e.y);
    }
    int trips = (cnt + 2) / 3;  // <= 22
    for (int p = 0; p < trips; p += 2) {
      int ja = 3 * p + g;
      int jb = ja + 3;
      int sa = __shfl(msrc, ja & 63); float wa = __shfl(mw, ja & 63);
      int sb = __shfl(msrc, jb & 63); float wb = __shfl(mw, jb & 63);
      wa = (act && ja < cnt) ? wa : 0.f;
      wb = (act && jb < cnt) ? wb : 0.f;
      unsigned ua = *(const unsigned*)(S2l + (size_t)sa * NCLASS);
      unsigned ub = *(const unsigned*)(S2l + (size_t)sb * NCLASS);
      acc0 += wa * bflo(ua) + wb * bflo(ub);
      acc1 += wa * bfhi(ua) + wb * bfhi(ub);
    }
  }
  // reduce the 3 groups: totals land in lanes 0..19
  float r0a = __shfl(acc0, (lane + 20) & 63);
  float r0b = __shfl(acc0, (lane + 40) & 63);
  float r1a = __shfl(acc1, (lane + 20) & 63);
  float r1b = __shfl(acc1, (lane + 40) & 63);
  float v0 = -INFINITY, v1 = -INFINITY;
  if (lane < 20) {
    float2 b = *(const float2*)(b2 + lane * 2);
    v0 = acc0 + r0a + r0b + b.x;
    v1 = acc1 + r1a + r1b + b.y;
  }
  float m = fmaxf(v0, v1);
#pragma unroll
  for (int off = 32; off; off >>= 1) m = fmaxf(m, __shfl_xor(m, off));
  float ex = (lane < 20) ? __expf(v0 - m) + __expf(v1 - m) : 0.f;
  float s = ex;
#pragma unroll
  for (int off = 32; off; off >>= 1) s += __shfl_xor(s, off);
  float lse = m + __logf(s);
  if (lane < 20) {
    float2 o = {v0 - lse, v1 - lse};
    *(float2*)(out + (size_t)wid * NCLASS + lane * 2) = o;
  }
}

// ---------------------------------------------------------------------------
extern "C" void kernel_launch(void* const* d_in, const int* in_sizes, int n_in,
                              void* d_out, int out_size, void* d_ws,
                              size_t ws_size, hipStream_t stream) {
  const float* x  = (const float*)d_in[0];
  const int* esrc = (const int*)d_in[1];
  const int* edst = (const int*)d_in[2];
  const float* ew = (const float*)d_in[3];
  const float* W1 = (const float*)d_in[4];
  const float* b1 = (const float*)d_in[5];
  const float* W2 = (const float*)d_in[6];
  const float* b2 = (const float*)d_in[7];
  float* out = (float*)d_out;

  const int M = in_sizes[0] / NFEAT;  // 100000
  const int E = in_sizes[1];          // 3200000
  const int nbkt = (M + BKT_NODES - 1) / BKT_NODES;  // 3125

  char* p = (char*)d_ws;
  ushort* support1 = (ushort*)p;           p += (size_t)M * NHID * 2;
  ushort* h        = (ushort*)p;           p += (size_t)M * NHID * 2;
  ushort* support2 = (ushort*)p;           p += (size_t)M * NCLASS * 2;
  ushort* W1t      = (ushort*)p;           p += (size_t)NFEAT * NHID * 2;
  int*    deg      = (int*)p;              p += (size_t)M * 4;
  int*    part     = (int*)p;              p += (size_t)M * 4;
  int*    rowptr   = (int*)p;              p += (size_t)M * 4;
  int*    gcursor  = (int*)p;              p += MAX_BKT * 4;
  int*    bsums    = (int*)p;              p += 512 * 4;
  int2*   ep       = (int2*)p;             p += (size_t)E * 8;
  int2*   tmp_sw   = (int2*)p;             p += (size_t)E * 8;
  int2*   ep2      = (int2*)p;             // E * 8

  const int nbScan = (M + 255) / 256;  // 391 <= 512

  // ---- CSR build: hist -> rowptr -> bucketed counting sorts ----
  hipMemsetAsync(deg, 0, (size_t)M * sizeof(int), stream);
  hist_kernel<<<(E + 255) / 256, 256, 0, stream>>>(edst, deg, E);
  scan1_kernel<<<nbScan, 256, 0, stream>>>(deg, part, bsums, M);
  scan2_kernel<<<1, 512, 0, stream>>>(bsums, nbScan);
  scan3_kernel<<<nbScan, 256, 0, stream>>>(part, bsums, deg, rowptr, M);
  initcur_kernel<<<(nbkt + 255) / 256, 256, 0, stream>>>(rowptr, gcursor, nbkt);
  binA_kernel<<<(E + BIN_EPB - 1) / BIN_EPB, 256, 0, stream>>>(
      esrc, edst, ew, gcursor, tmp_sw, E, nbkt);
  binB_kernel<<<nbkt, 256, 0, stream>>>(tmp_sw, rowptr, ep, M, E);
  binB2_kernel<<<nbkt, 256, 0, stream>>>(tmp_sw, rowptr, ep2, M, E);

  // ---- layer 1 ----
  w1t_kernel<<<(NFEAT * NHID) / 256, 256, 0, stream>>>(W1, W1t);
  dim3 g1(NHID / 128, (M + 127) / 128);
  gemm1_mfma<<<g1, 256, 0, stream>>>(x, W1t, support1, M);
  spmm1_lds_kernel<<<nbkt, 256, 0, stream>>>(support1, rowptr, ep2, b1, h, M, E);

  // ---- layer 2 ----
  gemm2_kernel<<<(M + 255) / 256, 256, 0, stream>>>(h, W2, support2, M);
  spmm2_csr_kernel<<<(M * 64 + 255) / 256, 256, 0, stream>>>(
      support2, rowptr, deg, ep, b2, out, M);
}